// Round 7
// baseline (383.900 us; speedup 1.0000x reference)
//
#include <hip/hip_runtime.h>
#include <math.h>

#define N_PTS 4096
#define DD 1024
#define DL 64
#define NEDGE (N_PTS - 1)
#define B_ROUNDS 12
#define NT 32    // 4096/128 tiles per dim
#define NBLK 256 // scan blocks per instance (16 rows each)

typedef __attribute__((ext_vector_type(8))) short short8;
typedef __attribute__((ext_vector_type(4))) float floatx4;
typedef __attribute__((ext_vector_type(4))) unsigned short ushortx4;

__device__ __forceinline__ unsigned short f2bf(float f) {
  unsigned u = __float_as_uint(f);
  u = u + 0x7FFFu + ((u >> 16) & 1u);  // RNE
  return (unsigned short)(u >> 16);
}

// ---------------- ae_loss + row sqnorm of y_true + fused bf16 convert ----------------
__global__ __launch_bounds__(256) void ae_sq_kernel(const float* __restrict__ yt,
                                                    const float* __restrict__ yp,
                                                    float* __restrict__ out,
                                                    float* __restrict__ sqD,
                                                    unsigned short* __restrict__ Xb) {
  int row = blockIdx.x, tid = threadIdx.x;
  const float4* a = (const float4*)(yt + (size_t)row * DD);
  const float4* b = (const float4*)(yp + (size_t)row * DD);
  float4 va = a[tid], vb = b[tid];
  ushortx4 o = {f2bf(va.x), f2bf(va.y), f2bf(va.z), f2bf(va.w)};
  *(ushortx4*)(Xb + (size_t)row * DD + tid * 4) = o;
  float e0 = va.x - vb.x, e1 = va.y - vb.y, e2 = va.z - vb.z, e3 = va.w - vb.w;
  float se = e0 * e0 + e1 * e1 + e2 * e2 + e3 * e3;
  float ss = va.x * va.x + va.y * va.y + va.z * va.z + va.w * va.w;
  for (int off = 32; off > 0; off >>= 1) {
    se += __shfl_down(se, off);
    ss += __shfl_down(ss, off);
  }
  __shared__ float sse[4], sss[4];
  int lane = tid & 63, w = tid >> 6;
  if (lane == 0) { sse[w] = se; sss[w] = ss; }
  __syncthreads();
  if (tid == 0) {
    out[row] = (sse[0] + sse[1] + sse[2] + sse[3]) * (1.0f / DD);
    sqD[row] = sss[0] + sss[1] + sss[2] + sss[3];
  }
}

__global__ __launch_bounds__(256) void sql_kernel(const float* __restrict__ lat,
                                                  float* __restrict__ sqL,
                                                  unsigned short* __restrict__ Lb) {
  int row = blockIdx.x * 4 + (threadIdx.x >> 6);
  int lane = threadIdx.x & 63;
  float v = lat[(size_t)row * DL + lane];
  Lb[(size_t)row * DL + lane] = f2bf(v);
  float s = v * v;
  for (int off = 32; off > 0; off >>= 1) s += __shfl_down(s, off);
  if (lane == 0) sqL[row] = s;
}

// ---------------- max of sq per space ----------------
__global__ __launch_bounds__(1024) void norm_kernel(const float* __restrict__ sqD,
                                                    const float* __restrict__ sqL,
                                                    unsigned int* __restrict__ normbits) {
  const float* s = blockIdx.x ? sqL : sqD;
  int tid = threadIdx.x;
  float m = fmaxf(fmaxf(s[tid], s[tid + 1024]), fmaxf(s[tid + 2048], s[tid + 3072]));
  for (int off = 32; off > 0; off >>= 1) m = fmaxf(m, __shfl_down(m, off));
  __shared__ float sm[16];
  int lane = tid & 63, w = tid >> 6;
  if (lane == 0) sm[w] = m;
  __syncthreads();
  if (tid == 0) {
    float mm = sm[0];
    for (int k = 1; k < 16; ++k) mm = fmaxf(mm, sm[k]);
    normbits[blockIdx.x] = __float_as_uint(mm);
  }
}

// ---------------- bf16 MFMA distance gemm -> scaled-u16 matrices (Round-5 body) -------
__global__ __launch_bounds__(256) void dist_mfma(const unsigned short* __restrict__ Xb,
                                                 const unsigned short* __restrict__ Lb,
                                                 const float* __restrict__ sqD,
                                                 const float* __restrict__ sqL,
                                                 unsigned short* __restrict__ dD,
                                                 unsigned short* __restrict__ dL,
                                                 const unsigned int* __restrict__ normbits,
                                                 unsigned int* __restrict__ maxbits) {
  int inst = blockIdx.y;
  const unsigned short* X = inst ? Lb : Xb;
  const float* sq = inst ? sqL : sqD;
  unsigned short* dist = inst ? dL : dD;
  int K = inst ? DL : DD;
  float scale = 65535.0f / (2.0f * sqrtf(__uint_as_float(normbits[inst])) + 1e-12f);

  int bi = 0, rem = blockIdx.x, span = NT;  // triangular decode, bi <= bj
  while (rem >= span) { rem -= span; ++bi; --span; }
  int bj = bi + rem;
  int row0 = bi * 128, col0 = bj * 128;

  __shared__ short As[128 * 40];
  __shared__ short Bs[128 * 40];
  int tid = threadIdx.x;
  int wave = tid >> 6, lane = tid & 63;
  int m = lane & 15, q = lane >> 4;
  int rw = (wave >> 1) * 64, cw = (wave & 1) * 64;

  floatx4 acc[4][4];
#pragma unroll
  for (int mi = 0; mi < 4; ++mi)
#pragma unroll
    for (int ni = 0; ni < 4; ++ni) acc[mi][ni] = {0.f, 0.f, 0.f, 0.f};

  int s0 = tid, s1 = tid + 256;
  int r0 = s0 >> 2, p0 = s0 & 3, r1 = s1 >> 2, p1 = s1 & 3;

  for (int k0 = 0; k0 < K; k0 += 32) {
    short8 a0 = *(const short8*)(X + (size_t)(row0 + r0) * K + k0 + p0 * 8);
    short8 a1 = *(const short8*)(X + (size_t)(row0 + r1) * K + k0 + p1 * 8);
    short8 b0 = *(const short8*)(X + (size_t)(col0 + r0) * K + k0 + p0 * 8);
    short8 b1 = *(const short8*)(X + (size_t)(col0 + r1) * K + k0 + p1 * 8);
    __syncthreads();
    *(short8*)&As[r0 * 40 + p0 * 8] = a0;
    *(short8*)&As[r1 * 40 + p1 * 8] = a1;
    *(short8*)&Bs[r0 * 40 + p0 * 8] = b0;
    *(short8*)&Bs[r1 * 40 + p1 * 8] = b1;
    __syncthreads();
    short8 aF[4], bF[4];
#pragma unroll
    for (int mi = 0; mi < 4; ++mi)
      aF[mi] = *(const short8*)&As[(rw + mi * 16 + m) * 40 + q * 8];
#pragma unroll
    for (int ni = 0; ni < 4; ++ni)
      bF[ni] = *(const short8*)&Bs[(cw + ni * 16 + m) * 40 + q * 8];
#pragma unroll
    for (int mi = 0; mi < 4; ++mi)
#pragma unroll
      for (int ni = 0; ni < 4; ++ni)
        acc[mi][ni] = __builtin_amdgcn_mfma_f32_16x16x32_bf16(aF[mi], bF[ni],
                                                              acc[mi][ni], 0, 0, 0);
  }

  float bmax = 0.f;
#pragma unroll
  for (int mi = 0; mi < 4; ++mi) {
    int i0 = row0 + rw + mi * 16 + q * 4;
    float s_i[4] = {sq[i0], sq[i0 + 1], sq[i0 + 2], sq[i0 + 3]};
#pragma unroll
    for (int ni = 0; ni < 4; ++ni) {
      int j = col0 + cw + ni * 16 + m;
      float sj = sq[j];
      ushortx4 tvec;
#pragma unroll
      for (int r = 0; r < 4; ++r) {
        float d2 = s_i[r] + sj - 2.f * acc[mi][ni][r];
        float d = d2 > 0.f ? sqrtf(d2) : 0.f;
        bmax = fmaxf(bmax, d);
        unsigned short u = (unsigned short)fminf(d * scale, 65535.0f);
        dist[(size_t)(i0 + r) * N_PTS + j] = u;
        tvec[r] = u;
      }
      *(ushortx4*)&dist[(size_t)j * N_PTS + i0] = tvec;
    }
  }
  if (inst == 0) {
    for (int off = 32; off > 0; off >>= 1) bmax = fmaxf(bmax, __shfl_down(bmax, off));
    __shared__ float bm[4];
    if (lane == 0) bm[wave] = bmax;
    __syncthreads();
    if (tid == 0)
      atomicMax(maxbits, __float_as_uint(fmaxf(fmaxf(bm[0], bm[1]), fmaxf(bm[2], bm[3]))));
  }
}

// ---------------- Boruvka ----------------
__global__ __launch_bounds__(256) void boruvka_init(unsigned short* __restrict__ comp,
                                                    unsigned long long* __restrict__ bestKey,
                                                    int* __restrict__ numRoots,
                                                    int* __restrict__ edgeCnt,
                                                    int* __restrict__ dcount) {
  int i = blockIdx.x * 256 + threadIdx.x;
  if (i < N_PTS) {
    comp[i] = (unsigned short)i;
    comp[N_PTS + i] = (unsigned short)i;
    bestKey[i] = ~0ULL;
    bestKey[N_PTS + i] = ~0ULL;
  }
  if (i == 0) {
    numRoots[0] = N_PTS; numRoots[1] = N_PTS;
    edgeCnt[0] = 0; edgeCnt[1] = 0;
    dcount[0] = 0; dcount[1] = 0;
  }
}

// One round: scan (all blocks) + merge (last-finishing block per instance).
// Cross-block comms INSIDE the kernel are exclusively device-scope atomics with
// threadfence release/acquire around the done-counter. comp/numRoots updates are
// plain stores consumed only by the NEXT dispatch (kernel-boundary coherence).
__global__ __launch_bounds__(256) void boruvka_round(const unsigned short* __restrict__ dD,
                                                     const unsigned short* __restrict__ dL,
                                                     unsigned short* __restrict__ comp,
                                                     unsigned long long* __restrict__ bestKey,
                                                     int* __restrict__ numRoots,
                                                     int2* __restrict__ edges,
                                                     int* __restrict__ edgeCnt,
                                                     int* __restrict__ dcount) {
  int inst = blockIdx.y;
  if (numRoots[inst] <= 1) return;
  const unsigned short* dist = inst ? dL : dD;
  unsigned short* compI = comp + (size_t)inst * N_PTS;
  unsigned long long* bkI = bestKey + (size_t)inst * N_PTS;

  __shared__ __align__(16) unsigned short comp_s[N_PTS];    // 8 KB
  __shared__ unsigned short parent_s[N_PTS];                // 8 KB (merge only)
  __shared__ unsigned long long wkey[16];
  __shared__ unsigned short wcomp[16];
  __shared__ int amLast, rootCnt;
  int tid = threadIdx.x;

  for (int i = tid; i < N_PTS / 8; i += 256)
    ((uint4*)comp_s)[i] = ((const uint4*)compI)[i];
  __syncthreads();

  // ---- scan: 4 waves x 4 interleaved rows ----
  int wave = tid >> 6, lane = tid & 63;
  int rbase = blockIdx.x * 16 + wave * 4;
  const uint4* rp[4];
  unsigned myc[4], bb[4];
  int bj[4];
#pragma unroll
  for (int k = 0; k < 4; ++k) {
    rp[k] = (const uint4*)(dist + (size_t)(rbase + k) * N_PTS);
    myc[k] = comp_s[rbase + k];
    bb[k] = 0xFFFFFFFFu;
    bj[k] = N_PTS;
  }
#pragma unroll
  for (int t = 0; t < 8; ++t) {
    int idx = lane + t * 64;
    uint4 vv[4] = {rp[0][idx], rp[1][idx], rp[2][idx], rp[3][idx]};
    uint4 cc = *(const uint4*)&comp_s[idx * 8];
    unsigned cv[8] = {cc.x & 0xFFFFu, cc.x >> 16, cc.y & 0xFFFFu, cc.y >> 16,
                      cc.z & 0xFFFFu, cc.z >> 16, cc.w & 0xFFFFu, cc.w >> 16};
    int j0 = idx * 8;
#pragma unroll
    for (int k = 0; k < 4; ++k) {
      unsigned dd[8] = {vv[k].x & 0xFFFFu, vv[k].x >> 16, vv[k].y & 0xFFFFu, vv[k].y >> 16,
                        vv[k].z & 0xFFFFu, vv[k].z >> 16, vv[k].w & 0xFFFFu, vv[k].w >> 16};
#pragma unroll
      for (int u = 0; u < 8; ++u)
        if (cv[u] != myc[k] && dd[u] < bb[k]) { bb[k] = dd[u]; bj[k] = j0 + u; }
    }
  }
#pragma unroll
  for (int k = 0; k < 4; ++k) {
    unsigned b = bb[k];
    int j = bj[k];
    for (int off = 32; off > 0; off >>= 1) {
      unsigned ob = __shfl_down(b, off);
      int oj = __shfl_down(j, off);
      if (ob < b || (ob == b && oj < j)) { b = ob; j = oj; }
    }
    if (lane == 0) {
      int slot = wave * 4 + k;
      if (j < N_PTS) {
        int row = rbase + k;
        int lo = row < j ? row : j, hi = row < j ? j : row;
        wkey[slot] = ((unsigned long long)b << 24) |
                     ((unsigned long long)lo << 12) | (unsigned long long)hi;
        wcomp[slot] = (unsigned short)myc[k];
      } else {
        wkey[slot] = ~0ULL;
      }
    }
  }
  __syncthreads();
  if (tid == 0) {
    for (int s = 0; s < 16; ++s) {  // dedupe by component -> spread atomics
      unsigned long long k = wkey[s];
      if (k == ~0ULL) continue;
      unsigned cmp = wcomp[s];
      for (int t2 = s + 1; t2 < 16; ++t2)
        if (wkey[t2] != ~0ULL && wcomp[t2] == cmp) {
          if (wkey[t2] < k) k = wkey[t2];
          wkey[t2] = ~0ULL;
        }
      atomicMin(&bkI[cmp], k);
    }
    __threadfence();  // release our atomicMins before signaling done
    int prev = atomicAdd(&dcount[inst], 1);
    amLast = (prev == NBLK - 1);
  }
  __syncthreads();
  if (!amLast) return;

  // ---- merge: this block only; comp_s already holds this instance's labels ----
  __threadfence();  // acquire side of the done-counter handshake
  if (tid == 0) rootCnt = 0;
  for (int c = tid; c < N_PTS; c += 256) {
    unsigned short p = (unsigned short)c;
    if (comp_s[c] == c) {  // root
      unsigned long long key =
          __hip_atomic_load(&bkI[c], __ATOMIC_RELAXED, __HIP_MEMORY_SCOPE_AGENT);
      if (key != ~0ULL) {
        int lo = (int)((key >> 12) & 0xFFF), hi = (int)(key & 0xFFF);
        int c2 = (comp_s[lo] == c) ? comp_s[hi] : comp_s[lo];
        unsigned long long k2 =
            __hip_atomic_load(&bkI[c2], __ATOMIC_RELAXED, __HIP_MEMORY_SCOPE_AGENT);
        bool mutual = (k2 == key);
        bool add;
        if (mutual) {
          if (c < c2) add = true;  // stays root, owns the shared edge
          else { p = (unsigned short)c2; add = false; }
        } else { p = (unsigned short)c2; add = true; }
        if (add) {
          int idx = atomicAdd(&edgeCnt[inst], 1);
          if (idx < NEDGE) edges[(size_t)inst * NEDGE + idx] = make_int2(lo, hi);
        }
      }
    }
    parent_s[c] = p;
  }
  __syncthreads();  // all key reads complete before any reset
  for (int c = tid; c < N_PTS; c += 256)
    if (comp_s[c] == c)
      __hip_atomic_store(&bkI[c], ~0ULL, __ATOMIC_RELAXED, __HIP_MEMORY_SCOPE_AGENT);
  for (int it = 0; it < 12; ++it) {  // pointer jumping (monotone races)
    __syncthreads();
    for (int c = tid; c < N_PTS; c += 256) parent_s[c] = parent_s[parent_s[c]];
  }
  __syncthreads();
  int local = 0;
  for (int c = tid; c < N_PTS; c += 256) {
    compI[c] = parent_s[comp_s[c]];
    if (comp_s[c] == c && parent_s[c] == c) local++;
  }
  atomicAdd(&rootCnt, local);
  __syncthreads();
  if (tid == 0) {
    numRoots[inst] = rootCnt;                 // read by NEXT dispatch
    __hip_atomic_store(&dcount[inst], 0, __ATOMIC_RELAXED, __HIP_MEMORY_SCOPE_AGENT);
    __threadfence();
  }
}

// ---------------- edge gather + topo losses ----------------
__global__ __launch_bounds__(256) void loss_kernel(const float* __restrict__ yt,
                                                   const float* __restrict__ lat,
                                                   const float* __restrict__ sqD,
                                                   const float* __restrict__ sqL,
                                                   const int2* __restrict__ edges_all,
                                                   const unsigned int* __restrict__ maxbits,
                                                   const float* __restrict__ latent_norm,
                                                   float* __restrict__ sums) {
  int wave = threadIdx.x >> 6, lane = threadIdx.x & 63;
  int g = blockIdx.x * 4 + wave;
  float inv_md = 1.f / __uint_as_float(*maxbits);
  float inv_ln = 1.f / latent_norm[0];
  float acc0 = 0.f, acc1 = 0.f;
  for (int t = 0; t < 8; ++t) {
    int e = g * 8 + t;
    if (e >= 2 * NEDGE) break;
    int2 ed = edges_all[e];
    int i = ed.x & (N_PTS - 1), j = ed.y & (N_PTS - 1);
    const float4* ai = (const float4*)(yt + (size_t)i * DD);
    const float4* aj = (const float4*)(yt + (size_t)j * DD);
    float dot = 0.f;
#pragma unroll
    for (int tt = 0; tt < 4; ++tt) {
      float4 x = ai[lane + tt * 64], y = aj[lane + tt * 64];
      dot += x.x * y.x + x.y * y.y + x.z * y.z + x.w * y.w;
    }
    float li = lat[(size_t)i * DL + lane], lj = lat[(size_t)j * DL + lane];
    float dotl = li * lj;
    for (int off = 32; off > 0; off >>= 1) {
      dot += __shfl_down(dot, off);
      dotl += __shfl_down(dotl, off);
    }
    if (lane == 0) {
      float d2 = sqD[i] + sqD[j] - 2.f * dot;
      float dd = (d2 > 0.f ? sqrtf(d2) : 0.f) * inv_md;
      float l2 = sqL[i] + sqL[j] - 2.f * dotl;
      float ld = (l2 > 0.f ? sqrtf(l2) : 0.f) * inv_ln;
      float df = dd - ld;
      if (e < NEDGE) acc0 += df * df; else acc1 += df * df;
    }
  }
  __shared__ float s0[4], s1[4];
  if (lane == 0) { s0[wave] = acc0; s1[wave] = acc1; }
  __syncthreads();
  if (threadIdx.x == 0) {
    float t0 = s0[0] + s0[1] + s0[2] + s0[3];
    float t1 = s1[0] + s1[1] + s1[2] + s1[3];
    if (t0 != 0.f) atomicAdd(&sums[0], t0);
    if (t1 != 0.f) atomicAdd(&sums[1], t1);
  }
}

__global__ __launch_bounds__(256) void finalize_kernel(float* __restrict__ out,
                                                       const float* __restrict__ sums) {
  int i = blockIdx.x * blockDim.x + threadIdx.x;
  float topo = (sums[0] + sums[1]) * (1.0f / NEDGE);
  out[i] += 0.5f * topo;  // REG_LAMBDA
}

extern "C" void kernel_launch(void* const* d_in, const int* in_sizes, int n_in,
                              void* d_out, int out_size, void* d_ws, size_t ws_size,
                              hipStream_t stream) {
  const float* y_true = (const float*)d_in[0];
  const float* latent = (const float*)d_in[1];
  const float* y_pred = (const float*)d_in[2];
  const float* latent_norm = (const float*)d_in[3];
  float* out = (float*)d_out;
  char* ws = (char*)d_ws;

  const size_t MAT16 = (size_t)N_PTS * N_PTS * 2;  // 32 MB per u16 matrix
  size_t off = 0;
  unsigned short* dD = (unsigned short*)(ws + off); off += MAT16;
  unsigned short* dL = (unsigned short*)(ws + off); off += MAT16;
  unsigned short* Xb = (unsigned short*)(ws + off); off += (size_t)N_PTS * DD * 2;
  unsigned short* Lb = (unsigned short*)(ws + off); off += (size_t)N_PTS * DL * 2;
  float* sqD = (float*)(ws + off); off += (size_t)N_PTS * 4;
  float* sqL = (float*)(ws + off); off += (size_t)N_PTS * 4;
  int2* edges = (int2*)(ws + off); off += (size_t)2 * NEDGE * 8 + 16;
  unsigned long long* bestKey = (unsigned long long*)(ws + off); off += (size_t)2 * N_PTS * 8;
  unsigned short* comp = (unsigned short*)(ws + off); off += (size_t)2 * N_PTS * 2;
  int* numRoots = (int*)(ws + off); off += 256;
  int* edgeCnt = numRoots + 2;
  unsigned int* maxbits = (unsigned int*)(edgeCnt + 2);
  float* sums = (float*)(maxbits + 1);
  unsigned int* normbits = (unsigned int*)(sums + 2);
  int* dcount = (int*)(normbits + 2);

  hipMemsetAsync(numRoots, 0, 256, stream);

  ae_sq_kernel<<<N_PTS, 256, 0, stream>>>(y_true, y_pred, out, sqD, Xb);
  sql_kernel<<<N_PTS / 4, 256, 0, stream>>>(latent, sqL, Lb);
  norm_kernel<<<2, 1024, 0, stream>>>(sqD, sqL, normbits);
  boruvka_init<<<N_PTS / 256, 256, 0, stream>>>(comp, bestKey, numRoots, edgeCnt, dcount);

  int tri = NT * (NT + 1) / 2;  // 528
  dist_mfma<<<dim3(tri, 2), 256, 0, stream>>>(Xb, Lb, sqD, sqL, dD, dL, normbits, maxbits);

  for (int r = 0; r < B_ROUNDS; ++r)
    boruvka_round<<<dim3(NBLK, 2), 256, 0, stream>>>(dD, dL, comp, bestKey, numRoots,
                                                     edges, edgeCnt, dcount);

  loss_kernel<<<256, 256, 0, stream>>>(y_true, latent, sqD, sqL, edges,
                                       maxbits, latent_norm, sums);
  finalize_kernel<<<N_PTS / 256, 256, 0, stream>>>(out, sums);
}